// Round 4
// baseline (137.486 us; speedup 1.0000x reference)
//
#include <hip/hip_runtime.h>
#include <math.h>

// Problem constants
#define BATCH 64
#define HH 512
#define WW 512
#define PAD 15
#define NELEM ((size_t)BATCH * HH * WW)
#define INV_KK (1.0f / 961.0f)

#define TILE_H 32              // rows per block (4 waves x 8 rows)
#define RPW 8                  // rows per wave
#define BPI (HH / TILE_H)      // 16 blocks per image
#define NBLK (BATCH * BPI)     // 1024 blocks
#define NXCD 8

typedef float f4 __attribute__((ext_vector_type(4)));

__device__ __forceinline__ float wave_reduce(float v) {
    #pragma unroll
    for (int off = 32; off; off >>= 1) v += __shfl_down(v, off, 64);
    return v;
}

// ---------------------------------------------------------------------------
// Fused kernel, barrier-free main loop. Each wave independently owns RPW=8
// rows of one image. Lane owns 8 contiguous columns c = 8*lane .. 8*lane+7:
//  - vertical 31-row rolling sums live in 8 registers (add/sub slide)
//  - horizontal 31-window via in-register prefix + wave shuffle scan +
//    17 fixed-offset shuffles (P[w+15] from lanes L+1/L+2, P[w-16] from L-2)
//  - loss math + per-wave accumulation; one barrier only for the final
//    4-wave block reduction.
// Block index is XCD-swizzled so each XCD owns 8 whole images -> all mask
// re-reads (init + slide + loss) are same-XCD L2 hits.
// ---------------------------------------------------------------------------
__global__ __launch_bounds__(256, 4) void fused_kernel(const float* __restrict__ pred,
                                                       const float* __restrict__ mask,
                                                       double* __restrict__ partials) {
    __shared__ float red[3][4];

    // XCD swizzle: final blockIdx f -> xcd = f%8 (HW round-robin). Give each
    // XCD 8 complete images: img = xcd*8 + slot/16, tile = slot%16.
    const int f    = blockIdx.x;
    const int xcd  = f & (NXCD - 1);
    const int slot = f >> 3;              // 0..127
    const int img  = xcd * 8 + (slot >> 4);
    const int tile = slot & (BPI - 1);

    const int tid  = threadIdx.x;
    const int lane = tid & 63;
    const int wv   = tid >> 6;
    const int h0   = tile * TILE_H + wv * RPW;   // first output row of this wave
    const int c    = lane * 8;                   // first column of this lane

    const float* mb = mask + (size_t)img * HH * WW;
    const float* pb = pred + (size_t)img * HH * WW;

    // --- init vertical window for row h0: mask rows [max(0,h0-15), min(511,h0+15)]
    float r0 = 0.f, r1 = 0.f, r2 = 0.f, r3 = 0.f, r4 = 0.f, r5 = 0.f, r6 = 0.f, r7 = 0.f;
    {
        int lo = h0 - PAD; if (lo < 0) lo = 0;
        int hi = h0 + PAD; if (hi > HH - 1) hi = HH - 1;
        for (int y = lo; y <= hi; ++y) {
            f4 m0 = *(const f4*)&mb[(size_t)y * WW + c];
            f4 m1 = *(const f4*)&mb[(size_t)y * WW + c + 4];
            r0 += m0.x; r1 += m0.y; r2 += m0.z; r3 += m0.w;
            r4 += m1.x; r5 += m1.y; r6 += m1.z; r7 += m1.w;
        }
    }

    float accb = 0.f, acci = 0.f, accu = 0.f;

    #pragma unroll
    for (int j = 0; j < RPW; ++j) {
        const int h = h0 + j;
        const size_t rb = (size_t)h * WW;

        // --- local inclusive prefix of the 8 vertical sums ---
        const float p0 = r0;
        const float p1 = p0 + r1;
        const float p2 = p1 + r2;
        const float p3 = p2 + r3;
        const float p4 = p3 + r4;
        const float p5 = p4 + r5;
        const float p6 = p5 + r6;
        const float p7 = p6 + r7;

        // --- wave inclusive scan of lane totals ---
        float incl = p7;
        #pragma unroll
        for (int off = 1; off < 64; off <<= 1) {
            float n = __shfl_up(incl, off, 64);
            if (lane >= off) incl += n;
        }
        const float excl = incl - p7;

        // inclusive prefix P[c+k] in registers
        const float P0 = excl + p0, P1 = excl + p1, P2 = excl + p2, P3 = excl + p3;
        const float P4 = excl + p4, P5 = excl + p5, P6 = excl + p6, P7 = excl + p7;

        // --- window sums S(w) = P[min(w+15,511)] - (w>=16 ? P[w-16] : 0) ---
        // w = 8L+k: hi pos k=0 -> lane L+1 idx7; k>=1 -> lane L+2 idx k-1.
        //           lo pos -> lane L-2 idx k (exists iff L>=2).
        const float top = __shfl(P7, 63, 64);          // P[511]
        const float hi0 = __shfl_down(P7, 1, 64);
        const float q0 = __shfl_down(P0, 2, 64);
        const float q1 = __shfl_down(P1, 2, 64);
        const float q2 = __shfl_down(P2, 2, 64);
        const float q3 = __shfl_down(P3, 2, 64);
        const float q4 = __shfl_down(P4, 2, 64);
        const float q5 = __shfl_down(P5, 2, 64);
        const float q6 = __shfl_down(P6, 2, 64);
        const float l0 = __shfl_up(P0, 2, 64);
        const float l1 = __shfl_up(P1, 2, 64);
        const float l2 = __shfl_up(P2, 2, 64);
        const float l3 = __shfl_up(P3, 2, 64);
        const float l4 = __shfl_up(P4, 2, 64);
        const float l5 = __shfl_up(P5, 2, 64);
        const float l6 = __shfl_up(P6, 2, 64);
        const float l7 = __shfl_up(P7, 2, 64);
        const bool okHi1 = (lane <= 62);
        const bool okHi2 = (lane <= 61);
        const bool hasLo = (lane >= 2);

        float S[8];
        S[0] = (okHi1 ? hi0 : top) - (hasLo ? l0 : 0.f);
        S[1] = (okHi2 ? q0  : top) - (hasLo ? l1 : 0.f);
        S[2] = (okHi2 ? q1  : top) - (hasLo ? l2 : 0.f);
        S[3] = (okHi2 ? q2  : top) - (hasLo ? l3 : 0.f);
        S[4] = (okHi2 ? q3  : top) - (hasLo ? l4 : 0.f);
        S[5] = (okHi2 ? q4  : top) - (hasLo ? l5 : 0.f);
        S[6] = (okHi2 ? q5  : top) - (hasLo ? l6 : 0.f);
        S[7] = (okHi2 ? q6  : top) - (hasLo ? l7 : 0.f);

        // --- loads for loss math (L2 hits: mask row h was read as 'add' 16 rows ago) ---
        const f4 mc0 = *(const f4*)&mb[rb + c];
        const f4 mc1 = *(const f4*)&mb[rb + c + 4];
        const f4 pc0 = *(const f4*)&pb[rb + c];
        const f4 pc1 = *(const f4*)&pb[rb + c + 4];
        const float mm[8] = {mc0.x, mc0.y, mc0.z, mc0.w, mc1.x, mc1.y, mc1.z, mc1.w};
        const float pp[8] = {pc0.x, pc0.y, pc0.z, pc0.w, pc1.x, pc1.y, pc1.z, pc1.w};

        #pragma unroll
        for (int k = 0; k < 8; ++k) {
            const float m  = mm[k];
            const float pr = pp[k];
            const float weit = 1.0f + 5.0f * fabsf(S[k] * INV_KK - m);
            const float e    = __expf(-fabsf(pr));
            const float bce  = fmaxf(pr, 0.f) - pr * m + __logf(1.0f + e);
            const float inv  = __builtin_amdgcn_rcpf(1.0f + e);
            const float p    = (pr >= 0.f) ? inv : e * inv;   // sigmoid(pr)
            accb += bce;
            acci += p * m * weit;
            accu += (p + m) * weit;
        }

        // --- slide the vertical window (wave-uniform branches) ---
        const int add = h + PAD + 1;
        const int sub = h - PAD;
        if (add < HH) {
            f4 a0 = *(const f4*)&mb[(size_t)add * WW + c];
            f4 a1 = *(const f4*)&mb[(size_t)add * WW + c + 4];
            r0 += a0.x; r1 += a0.y; r2 += a0.z; r3 += a0.w;
            r4 += a1.x; r5 += a1.y; r6 += a1.z; r7 += a1.w;
        }
        if (sub >= 0) {
            f4 s0 = *(const f4*)&mb[(size_t)sub * WW + c];
            f4 s1 = *(const f4*)&mb[(size_t)sub * WW + c + 4];
            r0 -= s0.x; r1 -= s0.y; r2 -= s0.z; r3 -= s0.w;
            r4 -= s1.x; r5 -= s1.y; r6 -= s1.z; r7 -= s1.w;
        }
    }

    // --- block reduction (the only barrier) ---
    accb = wave_reduce(accb);
    acci = wave_reduce(acci);
    accu = wave_reduce(accu);
    if (lane == 0) { red[0][wv] = accb; red[1][wv] = acci; red[2][wv] = accu; }
    __syncthreads();
    if (tid == 0) {
        double bt = (double)red[0][0] + red[0][1] + red[0][2] + red[0][3];
        double it = (double)red[1][0] + red[1][1] + red[1][2] + red[1][3];
        double ut = (double)red[2][0] + red[2][1] + red[2][2] + red[2][3];
        const size_t pidx = (size_t)img * BPI + tile;   // un-swizzled index
        partials[pidx * 3 + 0] = bt;
        partials[pidx * 3 + 1] = it;
        partials[pidx * 3 + 2] = ut;
    }
}

// ---------------------------------------------------------------------------
// Finalize from per-block partials (indexed img*BPI + tile).
// ---------------------------------------------------------------------------
__global__ __launch_bounds__(256) void finalize_kernel(const double* __restrict__ partials,
                                                       float* __restrict__ out) {
    __shared__ double redbce[4];
    int tid = threadIdx.x, lane = tid & 63, wv = tid >> 6;

    double bsum = 0.0;
    for (int i = tid; i < NBLK; i += 256) bsum += partials[(size_t)i * 3 + 0];
    #pragma unroll
    for (int off = 32; off; off >>= 1) bsum += __shfl_down(bsum, off, 64);
    if (lane == 0) redbce[wv] = bsum;
    __syncthreads();

    double wiou_term = 0.0;
    if (tid < 64) {
        int bb = tid;
        double it = 0.0, ut = 0.0;
        for (int j = 0; j < BPI; ++j) {
            it += partials[(size_t)(bb * BPI + j) * 3 + 1];
            ut += partials[(size_t)(bb * BPI + j) * 3 + 2];
        }
        wiou_term = 1.0 - (it + 1.0) / (ut - it + 1.0);
    }
    if (wv == 0) {
        #pragma unroll
        for (int off = 32; off; off >>= 1) wiou_term += __shfl_down(wiou_term, off, 64);
    }
    if (tid == 0) {
        double wbce = (redbce[0] + redbce[1] + redbce[2] + redbce[3]) / (double)NELEM;
        out[0] = (float)(wbce + wiou_term * (1.0 / 64.0));
    }
}

// ---------------------------------------------------------------------------
// Fallback path (tiny ws): recompute vertical sums in-kernel + atomics.
// ---------------------------------------------------------------------------
#define ACC_DOUBLES 129
__global__ __launch_bounds__(256) void rowpass_nows_kernel(const float* __restrict__ pred,
                                                           const float* __restrict__ mask,
                                                           double* __restrict__ acc) {
    __shared__ float vrow[WW];
    __shared__ float red[3][4];
    int b = blockIdx.x / HH;
    int h = blockIdx.x % HH;
    int lo = h - PAD; if (lo < 0) lo = 0;
    int hi = h + PAD; if (hi > HH - 1) hi = HH - 1;
    float s0 = 0.0f, s1 = 0.0f;
    const float* mb = mask + (size_t)b * HH * WW;
    for (int y = lo; y <= hi; ++y) {
        s0 += mb[(size_t)y * WW + threadIdx.x];
        s1 += mb[(size_t)y * WW + threadIdx.x + 256];
    }
    vrow[threadIdx.x]       = s0;
    vrow[threadIdx.x + 256] = s1;
    __syncthreads();

    size_t base = ((size_t)b * HH + h) * WW;
    float bce_p = 0.0f, inter_p = 0.0f, uni_p = 0.0f;
    for (int w = threadIdx.x; w < WW; w += 256) {
        int wlo = w - PAD; if (wlo < 0) wlo = 0;
        int whi = w + PAD; if (whi > WW - 1) whi = WW - 1;
        float s = 0.0f;
        for (int k = wlo; k <= whi; ++k) s += vrow[k];
        float m  = mask[base + w];
        float pr = pred[base + w];
        float weit = 1.0f + 5.0f * fabsf(s * INV_KK - m);
        float e   = expf(-fabsf(pr));
        float bce = fmaxf(pr, 0.0f) - pr * m + log1pf(e);
        float inv = 1.0f / (1.0f + e);
        float p   = (pr >= 0.0f) ? inv : e * inv;
        bce_p += bce; inter_p += p * m * weit; uni_p += (p + m) * weit;
    }
    int lane = threadIdx.x & 63, wvv = threadIdx.x >> 6;
    bce_p = wave_reduce(bce_p); inter_p = wave_reduce(inter_p); uni_p = wave_reduce(uni_p);
    if (lane == 0) { red[0][wvv] = bce_p; red[1][wvv] = inter_p; red[2][wvv] = uni_p; }
    __syncthreads();
    if (threadIdx.x == 0) {
        atomicAdd(&acc[0], (double)(red[0][0] + red[0][1] + red[0][2] + red[0][3]));
        atomicAdd(&acc[1 + b], (double)(red[1][0] + red[1][1] + red[1][2] + red[1][3]));
        atomicAdd(&acc[65 + b], (double)(red[2][0] + red[2][1] + red[2][2] + red[2][3]));
    }
}

__global__ void finalize_atomic_kernel(const double* __restrict__ acc, float* __restrict__ out) {
    int b = threadIdx.x;
    double inter = acc[1 + b];
    double uni   = acc[65 + b];
    double wiou = 1.0 - (inter + 1.0) / (uni - inter + 1.0);
    #pragma unroll
    for (int off = 32; off; off >>= 1) wiou += __shfl_down(wiou, off, 64);
    if (b == 0) {
        double wbce = acc[0] / (double)NELEM;
        out[0] = (float)(wbce + wiou * (1.0 / 64.0));
    }
}

// ---------------------------------------------------------------------------
extern "C" void kernel_launch(void* const* d_in, const int* in_sizes, int n_in,
                              void* d_out, int out_size, void* d_ws, size_t ws_size,
                              hipStream_t stream) {
    const float* pred = (const float*)d_in[0];
    const float* mask = (const float*)d_in[1];
    float* out = (float*)d_out;

    const size_t part_bytes = (size_t)NBLK * 3 * sizeof(double);   // 24 KiB

    if (ws_size >= part_bytes) {
        double* partials = (double*)d_ws;
        fused_kernel<<<NBLK, 256, 0, stream>>>(pred, mask, partials);
        finalize_kernel<<<1, 256, 0, stream>>>(partials, out);
    } else {
        double* acc = (double*)d_ws;
        hipMemsetAsync(acc, 0, ACC_DOUBLES * sizeof(double), stream);
        rowpass_nows_kernel<<<BATCH * HH, 256, 0, stream>>>(pred, mask, acc);
        finalize_atomic_kernel<<<1, 64, 0, stream>>>(acc, out);
    }
}

// Round 7
// 79.925 us; speedup vs baseline: 1.7202x; 1.7202x over previous
//
#include <hip/hip_runtime.h>
#include <math.h>

// Problem constants
#define BATCH 64
#define HH 512
#define WW 512
#define PAD 15
#define NELEM ((size_t)BATCH * HH * WW)
#define INV_KK (1.0f / 961.0f)

#define TILE_H 32              // rows per block (4 waves x 8 rows)
#define RPW 8                  // rows per wave
#define BPI (HH / TILE_H)      // 16 blocks per image
#define NBLK (BATCH * BPI)     // 1024 blocks
#define NXCD 8

typedef float f4 __attribute__((ext_vector_type(4)));

__device__ __forceinline__ float wave_reduce(float v) {
    #pragma unroll
    for (int off = 32; off; off >>= 1) v += __shfl_down(v, off, 64);
    return v;
}

// ---------------------------------------------------------------------------
// Fused kernel, barrier-free main loop. Each wave independently owns RPW=8
// rows of one image. Lane owns 8 contiguous columns c = 8*lane .. 8*lane+7:
//  - vertical 31-row rolling sums live in 8 registers (add/sub slide)
//  - horizontal 31-window via in-register prefix + wave shuffle scan +
//    17 fixed-offset shuffles (P[w+15] from lanes L+1/L+2, P[w-16] from L-2)
//  - loss math + per-wave accumulation; one barrier only for the final
//    4-wave block reduction.
// __launch_bounds__(256) with NO min-wave clause: R4's (256,4) capped the
// allocator at 64 VGPRs -> 142 MB scratch spill. Grid is 4 blocks/CU anyway.
// CRASH FIX (R5/R6): h0 = tile*32 + wv*8 maxes at 504, so the window-init
// upper row h0+PAD = 519 MUST be clamped to 511 (OOB page fault otherwise;
// also the reference's zero padding means clamping is the correct math).
// ---------------------------------------------------------------------------
__global__ __launch_bounds__(256) void fused_kernel(const float* __restrict__ pred,
                                                    const float* __restrict__ mask,
                                                    double* __restrict__ partials) {
    __shared__ float red[3][4];

    // XCD swizzle: final blockIdx f -> xcd = f%8 (HW round-robin). Give each
    // XCD 8 complete images: img = xcd*8 + slot/16, tile = slot%16.
    const int f    = blockIdx.x;
    const int xcd  = f & (NXCD - 1);
    const int slot = f >> 3;              // 0..127
    const int img  = xcd * 8 + (slot >> 4);
    const int tile = slot & (BPI - 1);

    const int tid  = threadIdx.x;
    const int lane = tid & 63;
    const int wv   = tid >> 6;
    const int h0   = tile * TILE_H + wv * RPW;   // first output row of this wave
    const int c    = lane * 8;                   // first column of this lane

    const float* mb = mask + (size_t)img * HH * WW;
    const float* pb = pred + (size_t)img * HH * WW;

    // --- init vertical window for row h0: mask rows [max(0,h0-15), min(511,h0+15)]
    float r0 = 0.f, r1 = 0.f, r2 = 0.f, r3 = 0.f, r4 = 0.f, r5 = 0.f, r6 = 0.f, r7 = 0.f;
    {
        int lo = h0 - PAD; if (lo < 0) lo = 0;
        int hi = h0 + PAD; if (hi > HH - 1) hi = HH - 1;   // CLAMP — see note above
        for (int y = lo; y <= hi; ++y) {
            f4 m0 = *(const f4*)&mb[(size_t)y * WW + c];
            f4 m1 = *(const f4*)&mb[(size_t)y * WW + c + 4];
            r0 += m0.x; r1 += m0.y; r2 += m0.z; r3 += m0.w;
            r4 += m1.x; r5 += m1.y; r6 += m1.z; r7 += m1.w;
        }
    }

    float accb = 0.f, acci = 0.f, accu = 0.f;

    #pragma unroll
    for (int j = 0; j < RPW; ++j) {
        const int h = h0 + j;
        const size_t rb = (size_t)h * WW;

        // --- local inclusive prefix of the 8 vertical sums ---
        const float p0 = r0;
        const float p1 = p0 + r1;
        const float p2 = p1 + r2;
        const float p3 = p2 + r3;
        const float p4 = p3 + r4;
        const float p5 = p4 + r5;
        const float p6 = p5 + r6;
        const float p7 = p6 + r7;

        // --- wave inclusive scan of lane totals ---
        float incl = p7;
        #pragma unroll
        for (int off = 1; off < 64; off <<= 1) {
            float n = __shfl_up(incl, off, 64);
            if (lane >= off) incl += n;
        }
        const float excl = incl - p7;

        // inclusive prefix P[c+k] in registers
        const float P0 = excl + p0, P1 = excl + p1, P2 = excl + p2, P3 = excl + p3;
        const float P4 = excl + p4, P5 = excl + p5, P6 = excl + p6, P7 = excl + p7;

        // --- window sums S(w) = P[min(w+15,511)] - (w>=16 ? P[w-16] : 0) ---
        // w = 8L+k: hi pos k=0 -> lane L+1 idx7; k>=1 -> lane L+2 idx k-1.
        //           lo pos -> lane L-2 idx k (exists iff L>=2).
        const float top = __shfl(P7, 63, 64);          // P[511]
        const float hi0 = __shfl_down(P7, 1, 64);
        const float q0 = __shfl_down(P0, 2, 64);
        const float q1 = __shfl_down(P1, 2, 64);
        const float q2 = __shfl_down(P2, 2, 64);
        const float q3 = __shfl_down(P3, 2, 64);
        const float q4 = __shfl_down(P4, 2, 64);
        const float q5 = __shfl_down(P5, 2, 64);
        const float q6 = __shfl_down(P6, 2, 64);
        const float l0 = __shfl_up(P0, 2, 64);
        const float l1 = __shfl_up(P1, 2, 64);
        const float l2 = __shfl_up(P2, 2, 64);
        const float l3 = __shfl_up(P3, 2, 64);
        const float l4 = __shfl_up(P4, 2, 64);
        const float l5 = __shfl_up(P5, 2, 64);
        const float l6 = __shfl_up(P6, 2, 64);
        const float l7 = __shfl_up(P7, 2, 64);
        const bool okHi1 = (lane <= 62);
        const bool okHi2 = (lane <= 61);
        const bool hasLo = (lane >= 2);

        float S[8];
        S[0] = (okHi1 ? hi0 : top) - (hasLo ? l0 : 0.f);
        S[1] = (okHi2 ? q0  : top) - (hasLo ? l1 : 0.f);
        S[2] = (okHi2 ? q1  : top) - (hasLo ? l2 : 0.f);
        S[3] = (okHi2 ? q2  : top) - (hasLo ? l3 : 0.f);
        S[4] = (okHi2 ? q3  : top) - (hasLo ? l4 : 0.f);
        S[5] = (okHi2 ? q4  : top) - (hasLo ? l5 : 0.f);
        S[6] = (okHi2 ? q5  : top) - (hasLo ? l6 : 0.f);
        S[7] = (okHi2 ? q6  : top) - (hasLo ? l7 : 0.f);

        // --- loads for loss math (L2 hits: mask row h was read as 'add' 16 rows ago) ---
        const f4 mc0 = *(const f4*)&mb[rb + c];
        const f4 mc1 = *(const f4*)&mb[rb + c + 4];
        const f4 pc0 = *(const f4*)&pb[rb + c];
        const f4 pc1 = *(const f4*)&pb[rb + c + 4];
        const float mm[8] = {mc0.x, mc0.y, mc0.z, mc0.w, mc1.x, mc1.y, mc1.z, mc1.w};
        const float pp[8] = {pc0.x, pc0.y, pc0.z, pc0.w, pc1.x, pc1.y, pc1.z, pc1.w};

        #pragma unroll
        for (int k = 0; k < 8; ++k) {
            const float m  = mm[k];
            const float pr = pp[k];
            const float weit = 1.0f + 5.0f * fabsf(S[k] * INV_KK - m);
            const float e    = __expf(-fabsf(pr));
            const float bce  = fmaxf(pr, 0.f) - pr * m + __logf(1.0f + e);
            const float inv  = __builtin_amdgcn_rcpf(1.0f + e);
            const float p    = (pr >= 0.f) ? inv : e * inv;   // sigmoid(pr)
            accb += bce;
            acci += p * m * weit;
            accu += (p + m) * weit;
        }

        // --- slide the vertical window (wave-uniform branches) ---
        const int add = h + PAD + 1;
        const int sub = h - PAD;
        if (add < HH) {
            f4 a0 = *(const f4*)&mb[(size_t)add * WW + c];
            f4 a1 = *(const f4*)&mb[(size_t)add * WW + c + 4];
            r0 += a0.x; r1 += a0.y; r2 += a0.z; r3 += a0.w;
            r4 += a1.x; r5 += a1.y; r6 += a1.z; r7 += a1.w;
        }
        if (sub >= 0) {
            f4 s0 = *(const f4*)&mb[(size_t)sub * WW + c];
            f4 s1 = *(const f4*)&mb[(size_t)sub * WW + c + 4];
            r0 -= s0.x; r1 -= s0.y; r2 -= s0.z; r3 -= s0.w;
            r4 -= s1.x; r5 -= s1.y; r6 -= s1.z; r7 -= s1.w;
        }
    }

    // --- block reduction (the only barrier) ---
    accb = wave_reduce(accb);
    acci = wave_reduce(acci);
    accu = wave_reduce(accu);
    if (lane == 0) { red[0][wv] = accb; red[1][wv] = acci; red[2][wv] = accu; }
    __syncthreads();
    if (tid == 0) {
        double bt = (double)red[0][0] + red[0][1] + red[0][2] + red[0][3];
        double it = (double)red[1][0] + red[1][1] + red[1][2] + red[1][3];
        double ut = (double)red[2][0] + red[2][1] + red[2][2] + red[2][3];
        const size_t pidx = (size_t)img * BPI + tile;   // un-swizzled index
        partials[pidx * 3 + 0] = bt;
        partials[pidx * 3 + 1] = it;
        partials[pidx * 3 + 2] = ut;
    }
}

// ---------------------------------------------------------------------------
// Finalize from per-block partials (indexed img*BPI + tile).
// ---------------------------------------------------------------------------
__global__ __launch_bounds__(256) void finalize_kernel(const double* __restrict__ partials,
                                                       float* __restrict__ out) {
    __shared__ double redbce[4];
    int tid = threadIdx.x, lane = tid & 63, wv = tid >> 6;

    double bsum = 0.0;
    for (int i = tid; i < NBLK; i += 256) bsum += partials[(size_t)i * 3 + 0];
    #pragma unroll
    for (int off = 32; off; off >>= 1) bsum += __shfl_down(bsum, off, 64);
    if (lane == 0) redbce[wv] = bsum;
    __syncthreads();

    double wiou_term = 0.0;
    if (tid < 64) {
        int bb = tid;
        double it = 0.0, ut = 0.0;
        for (int j = 0; j < BPI; ++j) {
            it += partials[(size_t)(bb * BPI + j) * 3 + 1];
            ut += partials[(size_t)(bb * BPI + j) * 3 + 2];
        }
        wiou_term = 1.0 - (it + 1.0) / (ut - it + 1.0);
    }
    if (wv == 0) {
        #pragma unroll
        for (int off = 32; off; off >>= 1) wiou_term += __shfl_down(wiou_term, off, 64);
    }
    if (tid == 0) {
        double wbce = (redbce[0] + redbce[1] + redbce[2] + redbce[3]) / (double)NELEM;
        out[0] = (float)(wbce + wiou_term * (1.0 / 64.0));
    }
}

// ---------------------------------------------------------------------------
// Fallback path (tiny ws): recompute vertical sums in-kernel + atomics.
// ---------------------------------------------------------------------------
#define ACC_DOUBLES 129
__global__ __launch_bounds__(256) void rowpass_nows_kernel(const float* __restrict__ pred,
                                                           const float* __restrict__ mask,
                                                           double* __restrict__ acc) {
    __shared__ float vrow[WW];
    __shared__ float red[3][4];
    int b = blockIdx.x / HH;
    int h = blockIdx.x % HH;
    int lo = h - PAD; if (lo < 0) lo = 0;
    int hi = h + PAD; if (hi > HH - 1) hi = HH - 1;
    float s0 = 0.0f, s1 = 0.0f;
    const float* mb = mask + (size_t)b * HH * WW;
    for (int y = lo; y <= hi; ++y) {
        s0 += mb[(size_t)y * WW + threadIdx.x];
        s1 += mb[(size_t)y * WW + threadIdx.x + 256];
    }
    vrow[threadIdx.x]       = s0;
    vrow[threadIdx.x + 256] = s1;
    __syncthreads();

    size_t base = ((size_t)b * HH + h) * WW;
    float bce_p = 0.0f, inter_p = 0.0f, uni_p = 0.0f;
    for (int w = threadIdx.x; w < WW; w += 256) {
        int wlo = w - PAD; if (wlo < 0) wlo = 0;
        int whi = w + PAD; if (whi > WW - 1) whi = WW - 1;
        float s = 0.0f;
        for (int k = wlo; k <= whi; ++k) s += vrow[k];
        float m  = mask[base + w];
        float pr = pred[base + w];
        float weit = 1.0f + 5.0f * fabsf(s * INV_KK - m);
        float e   = expf(-fabsf(pr));
        float bce = fmaxf(pr, 0.0f) - pr * m + log1pf(e);
        float inv = 1.0f / (1.0f + e);
        float p   = (pr >= 0.0f) ? inv : e * inv;
        bce_p += bce; inter_p += p * m * weit; uni_p += (p + m) * weit;
    }
    int lane = threadIdx.x & 63, wvv = threadIdx.x >> 6;
    bce_p = wave_reduce(bce_p); inter_p = wave_reduce(inter_p); uni_p = wave_reduce(uni_p);
    if (lane == 0) { red[0][wvv] = bce_p; red[1][wvv] = inter_p; red[2][wvv] = uni_p; }
    __syncthreads();
    if (threadIdx.x == 0) {
        atomicAdd(&acc[0], (double)(red[0][0] + red[0][1] + red[0][2] + red[0][3]));
        atomicAdd(&acc[1 + b], (double)(red[1][0] + red[1][1] + red[1][2] + red[1][3]));
        atomicAdd(&acc[65 + b], (double)(red[2][0] + red[2][1] + red[2][2] + red[2][3]));
    }
}

__global__ void finalize_atomic_kernel(const double* __restrict__ acc, float* __restrict__ out) {
    int b = threadIdx.x;
    double inter = acc[1 + b];
    double uni   = acc[65 + b];
    double wiou = 1.0 - (inter + 1.0) / (uni - inter + 1.0);
    #pragma unroll
    for (int off = 32; off; off >>= 1) wiou += __shfl_down(wiou, off, 64);
    if (b == 0) {
        double wbce = acc[0] / (double)NELEM;
        out[0] = (float)(wbce + wiou * (1.0 / 64.0));
    }
}

// ---------------------------------------------------------------------------
extern "C" void kernel_launch(void* const* d_in, const int* in_sizes, int n_in,
                              void* d_out, int out_size, void* d_ws, size_t ws_size,
                              hipStream_t stream) {
    const float* pred = (const float*)d_in[0];
    const float* mask = (const float*)d_in[1];
    float* out = (float*)d_out;

    const size_t part_bytes = (size_t)NBLK * 3 * sizeof(double);   // 24 KiB

    if (ws_size >= part_bytes) {
        double* partials = (double*)d_ws;
        fused_kernel<<<NBLK, 256, 0, stream>>>(pred, mask, partials);
        finalize_kernel<<<1, 256, 0, stream>>>(partials, out);
    } else {
        double* acc = (double*)d_ws;
        hipMemsetAsync(acc, 0, ACC_DOUBLES * sizeof(double), stream);
        rowpass_nows_kernel<<<BATCH * HH, 256, 0, stream>>>(pred, mask, acc);
        finalize_atomic_kernel<<<1, 64, 0, stream>>>(acc, out);
    }
}